// Round 2
// baseline (152.873 us; speedup 1.0000x reference)
//
#include <hip/hip_runtime.h>

#define IN_DIM 128
#define OUT_DIM 128

typedef __attribute__((ext_vector_type(8))) short short8v;   // 8 bf16 = 4 VGPRs
typedef __attribute__((ext_vector_type(4))) float float4v;
typedef __attribute__((ext_vector_type(4))) unsigned int uint4v;
typedef __attribute__((ext_vector_type(2))) unsigned int uint2v;
typedef __attribute__((ext_vector_type(2))) __fp16 half2v;

__device__ __forceinline__ ushort f2bf(float f) {
    unsigned int u = __builtin_bit_cast(unsigned int, f);
    unsigned int r = (u + 0x7fffu + ((u >> 16) & 1u)) >> 16;   // RNE
    return (ushort)r;
}

__device__ __forceinline__ unsigned int pk2bf(float x, float y) {
#if __has_builtin(__builtin_amdgcn_cvt_pk_bf16_f32)
    typedef __attribute__((ext_vector_type(2))) __bf16 bf2;
    bf2 r = __builtin_amdgcn_cvt_pk_bf16_f32(x, y);
    return __builtin_bit_cast(unsigned int, r);
#else
    return (unsigned int)f2bf(x) | ((unsigned int)f2bf(y) << 16);
#endif
}

__device__ __forceinline__ unsigned int pk2f16(float x, float y) {
    half2v r = __builtin_amdgcn_cvt_pkrtz(x, y);   // {lo: f16(x), hi: f16(y)}
    return __builtin_bit_cast(unsigned int, r);
}

// ---------------- Kernel 0: prep (Wt only, 16 blocks) ----------------
// Wt[n][k] = bf16(W[k][n]), row stride 136. Coalesced fp32 reads, b32 stores.
__global__ __launch_bounds__(256) void prep_kernel(const float* __restrict__ W,
                                                   ushort* __restrict__ Wt) {
    int k0 = blockIdx.x * 8;
    int n = threadIdx.x & 127;
    int half = threadIdx.x >> 7;
#pragma unroll
    for (int kp = 0; kp < 2; ++kp) {
        int k = k0 + (half * 2 + kp) * 2;
        float v0 = W[k * 128 + n];          // coalesced across lanes
        float v1 = W[(k + 1) * 128 + n];
        *(unsigned int*)&Wt[n * 136 + k] = pk2bf(v0, v1);
    }
}

// ---------------- Kernel 1: T(f16) = H @ W via MFMA, + rp tail ----------------
// Blocks [0, nb_gemm): 64-row x 128-col tile, K=128 unrolled (proven core).
// Epilogue: pack accumulators to f16 rows (v_cvt_pkrtz) -> T row = 256 B.
// Blocks [nb_gemm, ...): row_ptr[n] = lower_bound(edst, n) (overlaps gemm).
__global__ __launch_bounds__(256) void gemm_kernel(const float* __restrict__ H,
                                                   const ushort* __restrict__ Wt_g,
                                                   __fp16* __restrict__ T,
                                                   int M,
                                                   const int* __restrict__ edst,
                                                   int* __restrict__ rp,
                                                   int E, int nb_gemm) {
    __shared__ ushort Ws[128 * 136];   // 34816 B

    const int t = threadIdx.x;

    if (blockIdx.x >= nb_gemm) {       // rp tail blocks (block-uniform branch)
        int n = (blockIdx.x - nb_gemm) * 256 + t;
        if (n <= M) {
            int lo = 0, hi = E;
            while (lo < hi) {
                int mid = (lo + hi) >> 1;
                if (edst[mid] < n) lo = mid + 1; else hi = mid;
            }
            rp[n] = lo;
        }
        return;
    }

    const int row0 = blockIdx.x * 64;

#pragma unroll
    for (int f = t; f < 2176; f += 256)
        ((short8v*)Ws)[f] = ((const short8v*)Wt_g)[f];

    const int w = t >> 6;
    const int l = t & 63;
    const int m16 = l & 15;
    const int kq = (l >> 4) * 8;
    const int gr = row0 + w * 16 + m16;

    float4 h[8];
    if (gr < M) {
#pragma unroll
        for (int ks = 0; ks < 4; ++ks) {
            h[ks * 2]     = *(const float4*)&H[gr * 128 + ks * 32 + kq];
            h[ks * 2 + 1] = *(const float4*)&H[gr * 128 + ks * 32 + kq + 4];
        }
    } else {
#pragma unroll
        for (int i = 0; i < 8; ++i) h[i] = make_float4(0.f, 0.f, 0.f, 0.f);
    }

    short8v bfrag[4];
#pragma unroll
    for (int ks = 0; ks < 4; ++ks) {
        uint4v u;
        u[0] = pk2bf(h[ks * 2].x, h[ks * 2].y);
        u[1] = pk2bf(h[ks * 2].z, h[ks * 2].w);
        u[2] = pk2bf(h[ks * 2 + 1].x, h[ks * 2 + 1].y);
        u[3] = pk2bf(h[ks * 2 + 1].z, h[ks * 2 + 1].w);
        bfrag[ks] = __builtin_bit_cast(short8v, u);
    }

    __syncthreads();   // Ws ready

    float4v acc[8];
#pragma unroll
    for (int nt = 0; nt < 8; ++nt) acc[nt] = (float4v){0.f, 0.f, 0.f, 0.f};

#pragma unroll
    for (int ks = 0; ks < 4; ++ks) {
#pragma unroll
        for (int nt = 0; nt < 8; ++nt) {
            short8v afrag = *(const short8v*)&Ws[(nt * 16 + m16) * 136 + ks * 32 + kq];
            acc[nt] = __builtin_amdgcn_mfma_f32_16x16x32_bf16(afrag, bfrag[ks], acc[nt], 0, 0, 0);
        }
    }

    if (gr < M) {
        const int qd = l >> 4;
#pragma unroll
        for (int nt = 0; nt < 8; ++nt) {
            unsigned int u0 = pk2f16(acc[nt][0], acc[nt][1]);
            unsigned int u1 = pk2f16(acc[nt][2], acc[nt][3]);
            *(uint2v*)&T[gr * 128 + nt * 16 + qd * 4] = (uint2v){u0, u1};
        }
    }
}

// ---------------- Kernel 2: out[n][:] = b + sum_{e} w_e * T[src][:] ----------------
// One wave per node; lane owns 2 cols (one dword = 2 f16 of the row).
// Edge metadata via wave-uniform (scalar-pipe) loads: rp[] pulled through
// readfirstlane makes the loop counter provably uniform -> s_load per batch.
// Per edge: 1 gather dword + 2 v_fma_mix_f32 (f16->f32 convert folded into
// op_sel). No readlanes, no S scale, no int8 decode.
__global__ __launch_bounds__(256) void scatter_kernel(const __fp16* __restrict__ T,
                                                      const int* __restrict__ esrc,
                                                      const float* __restrict__ ew,
                                                      const int* __restrict__ rp,
                                                      const float* __restrict__ b,
                                                      float* __restrict__ out) {
    const int node = blockIdx.x * 4 + (threadIdx.x >> 6);
    const int lane = threadIdx.x & 63;

    const int s = __builtin_amdgcn_readfirstlane(rp[node]);
    const int e = __builtin_amdgcn_readfirstlane(rp[node + 1]);

    float2 bias = *(const float2*)&b[lane * 2];
    float ax = bias.x, ay = bias.y;

    const unsigned int lo = (unsigned int)(lane * 2);

    int c = s;
    for (; c + 8 <= e; c += 8) {
#pragma unroll
        for (int q = 0; q < 8; ++q) {
            const int   sq = esrc[c + q];     // uniform -> scalar pipe
            const float wq = ew[c + q];       // uniform -> scalar pipe
            half2v h = *(const half2v*)&T[(unsigned int)sq * 128u + lo];
            ax = fmaf((float)h.x, wq, ax);    // v_fma_mix_f32
            ay = fmaf((float)h.y, wq, ay);    // v_fma_mix_f32 (op_sel hi)
        }
    }
    for (; c < e; ++c) {
        const int   sq = esrc[c];
        const float wq = ew[c];
        half2v h = *(const half2v*)&T[(unsigned int)sq * 128u + lo];
        ax = fmaf((float)h.x, wq, ax);
        ay = fmaf((float)h.y, wq, ay);
    }

    *(float2*)&out[node * 128 + lane * 2] = make_float2(ax, ay);
}

extern "C" void kernel_launch(void* const* d_in, const int* in_sizes, int n_in,
                              void* d_out, int out_size, void* d_ws, size_t ws_size,
                              hipStream_t stream) {
    const float* H    = (const float*)d_in[0];
    const int*   esrc = (const int*)d_in[1];
    const int*   edst = (const int*)d_in[2];
    const float* ew   = (const float*)d_in[3];
    const float* W    = (const float*)d_in[4];
    const float* b    = (const float*)d_in[5];
    float* out = (float*)d_out;

    const int M = in_sizes[0] / IN_DIM;   // 50000 nodes
    const int E = in_sizes[1];            // 1,600,000 edges

    // Workspace layout
    __fp16* T = (__fp16*)d_ws;                                      // M*128*2 B
    size_t off = (size_t)M * 128 * 2;
    ushort* Wt = (ushort*)((char*)d_ws + off);                      // 128*136*2 B
    off += 128 * 136 * 2;
    int* rp = (int*)((char*)d_ws + off);                            // (M+1) ints

    // Wt transpose (16 blocks)
    prep_kernel<<<16, 256, 0, stream>>>(W, Wt);

    // gemm (f16 output) + rp tail blocks
    const int nb_gemm = (M + 63) / 64;         // 782
    const int nb_rp   = (M + 1 + 255) / 256;   // 196
    gemm_kernel<<<nb_gemm + nb_rp, 256, 0, stream>>>(H, Wt, T, M, edst, rp, E, nb_gemm);

    scatter_kernel<<<(M + 3) / 4, 256, 0, stream>>>(T, esrc, ew, rp, b, out);
}